// Round 27
// baseline (124.363 us; speedup 1.0000x reference)
//
#include <hip/hip_runtime.h>
#include <hip/hip_bf16.h>
#include <cstdint>

// Shapes (fixed by the reference)
static constexpr int LSEQ = 2048;
static constexpr int BB   = 2;
static constexpr int DM   = 1024;
static constexpr int NHD  = 16;   // heads
static constexpr int HD   = 64;   // head dim
static constexpr int ROWS = LSEQ * BB;   // 4096 tokens
static constexpr int NQKV = 3 * DM;      // 3072

typedef __attribute__((ext_vector_type(8)))  short v8s;   // 8 x bf16 (bits)
typedef __attribute__((ext_vector_type(4)))  float v4f;   // 16x16 C/D frag
typedef __attribute__((ext_vector_type(16))) float v16f;  // 32x32 C/D frag
typedef __attribute__((ext_vector_type(4)))  unsigned int v4u;
typedef __attribute__((ext_vector_type(2)))  unsigned int v2u;

#if __has_builtin(__builtin_amdgcn_exp2f)
#define EXP2F(x) __builtin_amdgcn_exp2f(x)
#else
#define EXP2F(x) __expf((x) * 0.69314718056f)
#endif

// fixed-max softmax constants: q pre-scaled by (1/8)*log2(e); bias = -10*log2(e)
static constexpr float QSCALE = 0.125f * 1.44269504089f;
static constexpr float NEGM   = -10.0f * 1.44269504089f;

__device__ __forceinline__ unsigned short f2bf(float f) {
    unsigned int u = __builtin_bit_cast(unsigned int, f);
    u += 0x7fffu + ((u >> 16) & 1u);          // RNE
    return (unsigned short)(u >> 16);
}

// global -> LDS direct copy, 16B per lane. LDS dest is wave-uniform base + lane*16.
__device__ __forceinline__ void gload_lds16(const void* g, void* l) {
    auto gp = (const __attribute__((address_space(1))) unsigned int*)(uintptr_t)g;
    auto lp = (__attribute__((address_space(3))) unsigned int*)(uintptr_t)l;
    __builtin_amdgcn_global_load_lds(gp, lp, 16, 0, 0);
}

// ---------------- fused producers: LN+cast (blocks 0..ROWS-1) | weight cast (rest) ----------------
__global__ __launch_bounds__(256) void prod_kernel(const float* __restrict__ x,
                                                   const float* __restrict__ w,
                                                   const float* __restrict__ bia,
                                                   const float* __restrict__ qkv_w,
                                                   const float* __restrict__ out_w,
                                                   unsigned short* __restrict__ xn,
                                                   unsigned short* __restrict__ wq,
                                                   unsigned short* __restrict__ wo) {
    const int t = threadIdx.x;
    if (blockIdx.x < ROWS) {
        const int row = blockIdx.x;
        const float* xr = x + (size_t)row * DM;
        float4 v = ((const float4*)xr)[t];
        float s  = v.x + v.y + v.z + v.w;
        float sq = v.x*v.x + v.y*v.y + v.z*v.z + v.w*v.w;
        #pragma unroll
        for (int off = 32; off > 0; off >>= 1) {
            s  += __shfl_down(s, off);
            sq += __shfl_down(sq, off);
        }
        __shared__ float red[8];
        const int wv = t >> 6;
        if ((t & 63) == 0) { red[wv] = s; red[4 + wv] = sq; }
        __syncthreads();
        if (t == 0) {
            float S = red[0] + red[1] + red[2] + red[3];
            float Q = red[4] + red[5] + red[6] + red[7];
            float mu  = S * (1.0f / DM);
            float var = Q * (1.0f / DM) - mu * mu;
            red[0] = mu;
            red[1] = rsqrtf(var + 1e-12f);
        }
        __syncthreads();
        const float mu = red[0], rs = red[1];
        float4 wv4 = ((const float4*)w)[t];
        float4 bv4 = ((const float4*)bia)[t];
        ushort4 o;
        o.x = f2bf((v.x - mu) * rs * wv4.x + bv4.x);
        o.y = f2bf((v.y - mu) * rs * wv4.y + bv4.y);
        o.z = f2bf((v.z - mu) * rs * wv4.z + bv4.z);
        o.w = f2bf((v.w - mu) * rs * wv4.w + bv4.w);
        ((ushort4*)(xn + (size_t)row * DM))[t] = o;
    } else {
        size_t i = ((size_t)(blockIdx.x - ROWS) * 256 + t) * 8;
        const float* src; unsigned short* dst; size_t off;
        if (i < (size_t)NQKV * DM) { src = qkv_w; dst = wq; off = i; }
        else                       { src = out_w; dst = wo; off = i - (size_t)NQKV * DM; }
        float4 a = *(const float4*)(src + off);
        float4 b = *(const float4*)(src + off + 4);
        ushort4 o0, o1;
        o0.x = f2bf(a.x); o0.y = f2bf(a.y); o0.z = f2bf(a.z); o0.w = f2bf(a.w);
        o1.x = f2bf(b.x); o1.y = f2bf(b.y); o1.z = f2bf(b.z); o1.w = f2bf(b.w);
        *(ushort4*)(dst + off)     = o0;
        *(ushort4*)(dst + off + 4) = o1;
    }
}

// ---------------- QKV GEMM: 256x192, 8 waves, SINGLE-buffer LDS (56 KB -> 2 blocks/CU) ----------------
// Per K-tile: STAGE -> __syncthreads (drain) -> COMPUTE -> __syncthreads. The drain stall is
// filled by the co-resident block's COMPUTE (m114 block-overlap) - the untested matrix cell:
// big tile (48 MFMA/wave/barrier) AND multi-block residency.
__global__ __launch_bounds__(512) void gemm1_kernel(const unsigned short* __restrict__ A,
                                                    const unsigned short* __restrict__ Bt,
                                                    const float* __restrict__ bias,
                                                    unsigned short* __restrict__ qb,
                                                    unsigned short* __restrict__ kb,
                                                    unsigned short* __restrict__ vt) {
    constexpr int K  = DM;
    constexpr int NT = K / 64;
    __shared__ unsigned short Al[256 * 64];
    __shared__ unsigned short Bl[192 * 64];
    constexpr int nbn = NQKV / 192;              // 16
    const int cpx = gridDim.x >> 3;
    const int sid = (blockIdx.x & 7) * cpx + (blockIdx.x >> 3);
    const int bm = sid / nbn;
    const int bn = sid % nbn;
    const int tid = threadIdx.x;
    const int w = tid >> 6, lane = tid & 63;
    const int l15 = lane & 15, l4 = lane >> 4;
    const int wm = w >> 2, wn = w & 3;           // 2 x 4; WM=128, WN=48
    const unsigned short* Ab = A  + (size_t)bm * 256 * K;
    const unsigned short* Bb = Bt + (size_t)bn * 192 * K;
    const int srow8  = lane >> 3;
    const int schunk = ((lane & 7) ^ (srow8 & 7)) * 8;
    const int swz    = l15 & 7;

    v4f acc[8][3] = {};

    auto STAGE = [&](int t) {
        const int k0 = t * 64;
        #pragma unroll
        for (int i = 0; i < 4; ++i) {            // A: 256/8/8 = 4 chunks/wave
            const int r0 = w * 32 + i * 8;
            gload_lds16(Ab + (size_t)(r0 + srow8) * K + k0 + schunk, &Al[r0 * 64]);
        }
        #pragma unroll
        for (int i = 0; i < 3; ++i) {            // B: 192/8/8 = 3 chunks/wave
            const int r0 = w * 24 + i * 8;
            gload_lds16(Bb + (size_t)(r0 + srow8) * K + k0 + schunk, &Bl[r0 * 64]);
        }
    };
    auto COMPUTE = [&]() {
        #pragma unroll
        for (int ks = 0; ks < 2; ++ks) {
            v8s af[8]; v8s bf[3];
            #pragma unroll
            for (int m = 0; m < 8; ++m) {
                const int row = wm * 128 + m * 16 + l15;
                af[m] = *(const v8s*)&Al[row * 64 + ((ks * 4 + l4) ^ swz) * 8];
            }
            #pragma unroll
            for (int n = 0; n < 3; ++n) {
                const int row = wn * 48 + n * 16 + l15;
                bf[n] = *(const v8s*)&Bl[row * 64 + ((ks * 4 + l4) ^ swz) * 8];
            }
            #pragma unroll
            for (int m = 0; m < 8; ++m)
                #pragma unroll
                for (int n = 0; n < 3; ++n)
                    acc[m][n] = __builtin_amdgcn_mfma_f32_16x16x32_bf16(af[m], bf[n], acc[m][n], 0, 0, 0);
        }
    };

    for (int t = 0; t < NT; ++t) {
        STAGE(t);
        __syncthreads();                 // vmcnt+lgkm drain; other block computes meanwhile
        COMPUTE();
        __syncthreads();                 // reads done before next STAGE overwrites
    }

    #pragma unroll
    for (int m = 0; m < 8; ++m) {
        #pragma unroll
        for (int n = 0; n < 3; ++n) {
            #pragma unroll
            for (int r = 0; r < 4; ++r) {
                const int row = bm * 256 + wm * 128 + m * 16 + l4 * 4 + r;
                const int col = bn * 192 + wn * 48 + n * 16 + l15;
                const float val = acc[m][n][r] + bias[col];
                const int lq = row >> 1, b = row & 1;      // row = l*B + b
                const int which = col >> 10, jr = col & 1023;
                const int h = jr >> 6, d = jr & 63;
                const int bh = b * NHD + h;
                if (which == 0)      qb[((size_t)bh * LSEQ + lq) * HD + d] = f2bf(val * QSCALE);
                else if (which == 1) kb[((size_t)bh * LSEQ + lq) * HD + d] = f2bf(val);
                else                 vt[((size_t)bh * HD + d) * LSEQ + lq] = f2bf(val);
            }
        }
    }
}

// ---------------- out-proj GEMM: 128x64 dbuf + counted vmcnt (r13 form) ----------------
template <int BM, int BN>
__global__ __launch_bounds__(256)
void gemm2_kernel(const unsigned short* __restrict__ A,
                  const unsigned short* __restrict__ Bt,
                  const float* __restrict__ bias,
                  float* __restrict__ outF,
                  int N) {
    constexpr int K  = DM;
    constexpr int NW = 4;
    constexpr int NWN = NW / 2;
    constexpr int WM = BM / 2;
    constexpr int WN = BN / NWN;
    constexpr int MR = WM / 16;
    constexpr int FC = WN / 16;
    constexpr int NT = K / 64;
    constexpr int LPS = (BM + BN) / NW / 8;
    __shared__ unsigned short Al[2][BM * 64];
    __shared__ unsigned short Bl[2][BN * 64];
    const int nbn = N / BN;
    const int cpx = gridDim.x >> 3;
    const int sid = (blockIdx.x & 7) * cpx + (blockIdx.x >> 3);
    const int bm = sid / nbn;
    const int bn = sid % nbn;
    const int tid = threadIdx.x;
    const int w = tid >> 6, lane = tid & 63;
    const int l15 = lane & 15, l4 = lane >> 4;
    const int wm = w / NWN, wn = w % NWN;
    const unsigned short* Ab = A  + (size_t)bm * BM * K;
    const unsigned short* Bb = Bt + (size_t)bn * BN * K;
    const int srow8  = lane >> 3;
    const int schunk = ((lane & 7) ^ (srow8 & 7)) * 8;
    const int swz    = l15 & 7;

    v4f acc[MR][FC] = {};

    auto STAGE = [&](int buf, int t) {
        const int k0 = t * 64;
        #pragma unroll
        for (int i = 0; i < BM / 8 / NW; ++i) {
            const int r0 = w * (BM / NW) + i * 8;
            gload_lds16(Ab + (size_t)(r0 + srow8) * K + k0 + schunk, &Al[buf][r0 * 64]);
        }
        #pragma unroll
        for (int i = 0; i < BN / 8 / NW; ++i) {
            const int r0 = w * (BN / NW) + i * 8;
            gload_lds16(Bb + (size_t)(r0 + srow8) * K + k0 + schunk, &Bl[buf][r0 * 64]);
        }
    };
    auto COMPUTE = [&](int buf) {
        #pragma unroll
        for (int ks = 0; ks < 2; ++ks) {
            v8s af[MR]; v8s bf[FC];
            #pragma unroll
            for (int m = 0; m < MR; ++m) {
                const int row = wm * WM + m * 16 + l15;
                af[m] = *(const v8s*)&Al[buf][row * 64 + ((ks * 4 + l4) ^ swz) * 8];
            }
            #pragma unroll
            for (int n = 0; n < FC; ++n) {
                const int row = wn * WN + n * 16 + l15;
                bf[n] = *(const v8s*)&Bl[buf][row * 64 + ((ks * 4 + l4) ^ swz) * 8];
            }
            #pragma unroll
            for (int m = 0; m < MR; ++m)
                #pragma unroll
                for (int n = 0; n < FC; ++n)
                    acc[m][n] = __builtin_amdgcn_mfma_f32_16x16x32_bf16(af[m], bf[n], acc[m][n], 0, 0, 0);
        }
    };

    STAGE(0, 0);
    int cur = 0;
    for (int t = 0; t < NT; ++t) {
        if (t + 1 < NT) {
            STAGE(cur ^ 1, t + 1);
            if constexpr (LPS == 6) asm volatile("s_waitcnt vmcnt(6)" ::: "memory");
            else                    asm volatile("s_waitcnt vmcnt(0)" ::: "memory");
        } else {
            asm volatile("s_waitcnt vmcnt(0)" ::: "memory");
        }
        __builtin_amdgcn_s_barrier();
        __builtin_amdgcn_sched_barrier(0);
        COMPUTE(cur);
        __builtin_amdgcn_s_barrier();
        cur ^= 1;
    }

    #pragma unroll
    for (int m = 0; m < MR; ++m)
        #pragma unroll
        for (int n = 0; n < FC; ++n)
            #pragma unroll
            for (int r = 0; r < 4; ++r) {
                const int row = bm * BM + wm * WM + m * 16 + l4 * 4 + r;
                const int col = bn * BN + wn * WN + n * 16 + l15;
                outF[(size_t)row * N + col] = acc[m][n][r] + bias[col];
            }
}

// ---------------- flash attention: swapped QK^T (32x32), in-register P ----------------
// Counted-vmcnt pipeline; mask bias in MFMA C-init; permlane32_swap P-frags; setprio.
__global__ __launch_bounds__(256) void attn_kernel(const unsigned short* __restrict__ qbuf,
                                                   const unsigned short* __restrict__ kbuf,
                                                   const unsigned short* __restrict__ vtbuf,
                                                   const int* __restrict__ amask,
                                                   unsigned short* __restrict__ ctx) {
    __shared__ unsigned short Kl[2][64 * 64];
    __shared__ unsigned short Vl[2][64 * 64];
    __shared__ alignas(16) float mb_all[LSEQ];
    __shared__ alignas(16) float inv_l[4 * 32];
    const int id = blockIdx.x;
    const int inner = id >> 3;
    const int bh = (id & 7) * 4 + (inner & 3);
    const int qblk = inner >> 2;
    const int bat = bh >> 4, h = bh & 15;
    const int tid = threadIdx.x;
    const int w = tid >> 6, lane = tid & 63;
    const int l31 = lane & 31, hi = lane >> 5;
    const int q0 = qblk * 128 + w * 32;

    #pragma unroll
    for (int i = 0; i < LSEQ / 256; ++i)
        mb_all[i * 256 + tid] = amask[bat * LSEQ + i * 256 + tid] ? NEGM : -1e30f;

    const unsigned short* Qp = qbuf + ((size_t)bh * LSEQ + q0 + l31) * HD + hi * 8;
    v8s qfr[4];
    #pragma unroll
    for (int s = 0; s < 4; ++s) qfr[s] = *(const v8s*)(Qp + s * 16);

    const unsigned short* Kb = kbuf  + (size_t)bh * LSEQ * HD;
    const unsigned short* Vb = vtbuf + (size_t)bh * HD * LSEQ;

    v16f O0 = {}, O1 = {};
    float ls0 = 0.f, ls1 = 0.f, ls2 = 0.f, ls3 = 0.f;

    const int srow = lane >> 3;
    const int schunk = ((lane & 7) ^ srow) * 8;
    const int rsw = l31 & 7;

    auto STAGE = [&](int buf, int kv0) {
        const int r0 = w * 16;
        gload_lds16(Kb + (size_t)(kv0 + r0 + srow) * HD + schunk,       &Kl[buf][r0 * 64]);
        gload_lds16(Kb + (size_t)(kv0 + r0 + 8 + srow) * HD + schunk,   &Kl[buf][(r0 + 8) * 64]);
        gload_lds16(Vb + (size_t)(r0 + srow) * LSEQ + kv0 + schunk,     &Vl[buf][r0 * 64]);
        gload_lds16(Vb + (size_t)(r0 + 8 + srow) * LSEQ + kv0 + schunk, &Vl[buf][(r0 + 8) * 64]);
    };

    STAGE(0, 0);
    __syncthreads();                       // drains tile0 loads + mb_all writes (once)
    int cur = 0;
    for (int t = 0; t < LSEQ / 64; ++t) {
        if (t + 1 < LSEQ / 64) {
            STAGE(cur ^ 1, (t + 1) * 64);  // 4 loads issued; 8 outstanding
            asm volatile("s_waitcnt vmcnt(4)" ::: "memory");   // tile t's 4 landed
        } else {
            asm volatile("s_waitcnt vmcnt(0)" ::: "memory");
        }
        __builtin_amdgcn_s_barrier();      // publish tile t across waves
        __builtin_amdgcn_sched_barrier(0);
        const int kv0 = t * 64;

        #pragma unroll
        for (int kvh = 0; kvh < 2; ++kvh) {
            float4 mbv[4];
            #pragma unroll
            for (int g = 0; g < 4; ++g)
                mbv[g] = *(const float4*)&mb_all[kv0 + kvh * 32 + g * 8 + hi * 4];
            v16f sc;
            #pragma unroll
            for (int g = 0; g < 4; ++g) {
                sc[g * 4 + 0] = mbv[g].x;
                sc[g * 4 + 1] = mbv[g].y;
                sc[g * 4 + 2] = mbv[g].z;
                sc[g * 4 + 3] = mbv[g].w;
            }
            v8s kf[4];
            #pragma unroll
            for (int s = 0; s < 4; ++s)
                kf[s] = *(const v8s*)&Kl[cur][(kvh * 32 + l31) * 64 + ((2 * s + hi) ^ rsw) * 8];
            __builtin_amdgcn_s_setprio(1);
            #pragma unroll
            for (int s = 0; s < 4; ++s)
                sc = __builtin_amdgcn_mfma_f32_32x32x16_bf16(kf[s], qfr[s], sc, 0, 0, 0);
            __builtin_amdgcn_s_setprio(0);
            float pf[16];
            #pragma unroll
            for (int g = 0; g < 4; ++g) {
                const float p0 = EXP2F(sc[g * 4 + 0]);
                const float p1 = EXP2F(sc[g * 4 + 1]);
                const float p2 = EXP2F(sc[g * 4 + 2]);
                const float p3 = EXP2F(sc[g * 4 + 3]);
                pf[g * 4 + 0] = p0; pf[g * 4 + 1] = p1;
                pf[g * 4 + 2] = p2; pf[g * 4 + 3] = p3;
                ls0 += p0; ls1 += p1; ls2 += p2; ls3 += p3;
            }
            #pragma unroll
            for (int c = 0; c < 2; ++c) {
                unsigned int W[4];
                #pragma unroll
                for (int k = 0; k < 4; ++k)
                    asm("v_cvt_pk_bf16_f32 %0, %1, %2"
                        : "=v"(W[k]) : "v"(pf[8 * c + 2 * k]), "v"(pf[8 * c + 2 * k + 1]));
                v4u fw;
#if __has_builtin(__builtin_amdgcn_permlane32_swap)
                const v2u r02 = __builtin_amdgcn_permlane32_swap(W[0], W[2], false, false);
                const v2u r13 = __builtin_amdgcn_permlane32_swap(W[1], W[3], false, false);
                fw.x = r02.x; fw.y = r13.x; fw.z = r02.y; fw.w = r13.y;
#else
                const unsigned int sel0 = hi ? W[0] : W[2];
                const unsigned int sel1 = hi ? W[1] : W[3];
                const unsigned int S0 = (unsigned int)__shfl_xor((int)sel0, 32);
                const unsigned int S1 = (unsigned int)__shfl_xor((int)sel1, 32);
                fw.x = hi ? S0 : W[0];
                fw.y = hi ? S1 : W[1];
                fw.z = hi ? W[2] : S0;
                fw.w = hi ? W[3] : S1;
#endif
                const v8s pa = __builtin_bit_cast(v8s, fw);
                const int vch = (kvh * 4 + c * 2 + hi);
                const v8s vf0 = *(const v8s*)&Vl[cur][(l31) * 64      + (vch ^ rsw) * 8];
                const v8s vf1 = *(const v8s*)&Vl[cur][(32 + l31) * 64 + (vch ^ rsw) * 8];
                __builtin_amdgcn_s_setprio(1);
                O0 = __builtin_amdgcn_mfma_f32_32x32x16_bf16(pa, vf0, O0, 0, 0, 0);
                O1 = __builtin_amdgcn_mfma_f32_32x32x16_bf16(pa, vf1, O1, 0, 0, 0);
                __builtin_amdgcn_s_setprio(0);
            }
        }
        __builtin_amdgcn_s_barrier();      // reads of buf cur done before t+2 overwrites
        cur ^= 1;
    }

    float lsum = (ls0 + ls1) + (ls2 + ls3);
    lsum += __shfl_xor(lsum, 32);
    if (hi == 0) inv_l[w * 32 + l31] = 1.0f / lsum;
    asm volatile("s_waitcnt lgkmcnt(0)" ::: "memory");
    __builtin_amdgcn_sched_barrier(0);

    #pragma unroll
    for (int g = 0; g < 4; ++g) {
        const float4 iv = *(const float4*)&inv_l[w * 32 + g * 8 + hi * 4];
        #pragma unroll
        for (int bq = 0; bq < 4; ++bq) {
            const float ivx = (bq == 0) ? iv.x : (bq == 1) ? iv.y : (bq == 2) ? iv.z : iv.w;
            const int lq = q0 + g * 8 + hi * 4 + bq;
            unsigned short* crow = ctx + ((size_t)lq * BB + bat) * DM + h * HD;
            crow[l31]      = f2bf(O0[g * 4 + bq] * ivx);
            crow[32 + l31] = f2bf(O1[g * 4 + bq] * ivx);
        }
    }
}

extern "C" void kernel_launch(void* const* d_in, const int* in_sizes, int n_in,
                              void* d_out, int out_size, void* d_ws, size_t ws_size,
                              hipStream_t stream) {
    (void)in_sizes; (void)n_in; (void)out_size; (void)ws_size;
    const float* x     = (const float*)d_in[0];
    const int*   amask = (const int*)d_in[1];
    const float* ln_w  = (const float*)d_in[2];
    const float* ln_b  = (const float*)d_in[3];
    const float* qkv_w = (const float*)d_in[4];
    const float* qkv_b = (const float*)d_in[5];
    const float* out_w = (const float*)d_in[6];
    const float* out_b = (const float*)d_in[7];
    float* out = (float*)d_out;

    unsigned short* ws    = (unsigned short*)d_ws;
    unsigned short* xn    = ws;                                   // 4096*1024
    unsigned short* wq    = xn + (size_t)ROWS * DM;               // 3072*1024
    unsigned short* wo    = wq + (size_t)NQKV * DM;               // 1024*1024
    unsigned short* qbuf  = wo + (size_t)DM * DM;                 // 32*2048*64
    unsigned short* kbuf  = qbuf + (size_t)BB * NHD * LSEQ * HD;
    unsigned short* vtbuf = kbuf + (size_t)BB * NHD * LSEQ * HD;
    unsigned short* ctx   = vtbuf + (size_t)BB * NHD * LSEQ * HD; // 4096*1024

    prod_kernel<<<ROWS + 2048, 256, 0, stream>>>(x, ln_w, ln_b, qkv_w, out_w, xn, wq, wo);
    gemm1_kernel<<<(ROWS / 256) * (NQKV / 192), 512, 0, stream>>>(
        xn, wq, qkv_b, qbuf, kbuf, vtbuf);
    attn_kernel<<<512, 256, 0, stream>>>(qbuf, kbuf, vtbuf, amask, ctx);
    gemm2_kernel<128, 64><<<(ROWS / 128) * (DM / 64), 256, 0, stream>>>(
        ctx, wo, out_b, out, DM);
}

// Round 28
// 119.076 us; speedup vs baseline: 1.0444x; 1.0444x over previous
//
#include <hip/hip_runtime.h>
#include <hip/hip_bf16.h>
#include <cstdint>

// Shapes (fixed by the reference)
static constexpr int LSEQ = 2048;
static constexpr int BB   = 2;
static constexpr int DM   = 1024;
static constexpr int NHD  = 16;   // heads
static constexpr int HD   = 64;   // head dim
static constexpr int ROWS = LSEQ * BB;   // 4096 tokens
static constexpr int NQKV = 3 * DM;      // 3072

typedef __attribute__((ext_vector_type(8)))  short v8s;   // 8 x bf16 (bits)
typedef __attribute__((ext_vector_type(4)))  float v4f;   // 16x16 C/D frag
typedef __attribute__((ext_vector_type(16))) float v16f;  // 32x32 C/D frag
typedef __attribute__((ext_vector_type(4)))  unsigned int v4u;
typedef __attribute__((ext_vector_type(2)))  unsigned int v2u;

#if __has_builtin(__builtin_amdgcn_exp2f)
#define EXP2F(x) __builtin_amdgcn_exp2f(x)
#else
#define EXP2F(x) __expf((x) * 0.69314718056f)
#endif

// fixed-max softmax constants: q pre-scaled by (1/8)*log2(e); bias = -10*log2(e)
static constexpr float QSCALE = 0.125f * 1.44269504089f;
static constexpr float NEGM   = -10.0f * 1.44269504089f;

__device__ __forceinline__ unsigned short f2bf(float f) {
    unsigned int u = __builtin_bit_cast(unsigned int, f);
    u += 0x7fffu + ((u >> 16) & 1u);          // RNE
    return (unsigned short)(u >> 16);
}

// global -> LDS direct copy, 16B per lane. LDS dest is wave-uniform base + lane*16.
__device__ __forceinline__ void gload_lds16(const void* g, void* l) {
    auto gp = (const __attribute__((address_space(1))) unsigned int*)(uintptr_t)g;
    auto lp = (__attribute__((address_space(3))) unsigned int*)(uintptr_t)l;
    __builtin_amdgcn_global_load_lds(gp, lp, 16, 0, 0);
}

// ---------------- fused producers: LN+cast (blocks 0..ROWS-1) | weight cast (rest) ----------------
__global__ __launch_bounds__(256) void prod_kernel(const float* __restrict__ x,
                                                   const float* __restrict__ w,
                                                   const float* __restrict__ bia,
                                                   const float* __restrict__ qkv_w,
                                                   const float* __restrict__ out_w,
                                                   unsigned short* __restrict__ xn,
                                                   unsigned short* __restrict__ wq,
                                                   unsigned short* __restrict__ wo) {
    const int t = threadIdx.x;
    if (blockIdx.x < ROWS) {
        const int row = blockIdx.x;
        const float* xr = x + (size_t)row * DM;
        float4 v = ((const float4*)xr)[t];
        float s  = v.x + v.y + v.z + v.w;
        float sq = v.x*v.x + v.y*v.y + v.z*v.z + v.w*v.w;
        #pragma unroll
        for (int off = 32; off > 0; off >>= 1) {
            s  += __shfl_down(s, off);
            sq += __shfl_down(sq, off);
        }
        __shared__ float red[8];
        const int wv = t >> 6;
        if ((t & 63) == 0) { red[wv] = s; red[4 + wv] = sq; }
        __syncthreads();
        if (t == 0) {
            float S = red[0] + red[1] + red[2] + red[3];
            float Q = red[4] + red[5] + red[6] + red[7];
            float mu  = S * (1.0f / DM);
            float var = Q * (1.0f / DM) - mu * mu;
            red[0] = mu;
            red[1] = rsqrtf(var + 1e-12f);
        }
        __syncthreads();
        const float mu = red[0], rs = red[1];
        float4 wv4 = ((const float4*)w)[t];
        float4 bv4 = ((const float4*)bia)[t];
        ushort4 o;
        o.x = f2bf((v.x - mu) * rs * wv4.x + bv4.x);
        o.y = f2bf((v.y - mu) * rs * wv4.y + bv4.y);
        o.z = f2bf((v.z - mu) * rs * wv4.z + bv4.z);
        o.w = f2bf((v.w - mu) * rs * wv4.w + bv4.w);
        ((ushort4*)(xn + (size_t)row * DM))[t] = o;
    } else {
        size_t i = ((size_t)(blockIdx.x - ROWS) * 256 + t) * 8;
        const float* src; unsigned short* dst; size_t off;
        if (i < (size_t)NQKV * DM) { src = qkv_w; dst = wq; off = i; }
        else                       { src = out_w; dst = wo; off = i - (size_t)NQKV * DM; }
        float4 a = *(const float4*)(src + off);
        float4 b = *(const float4*)(src + off + 4);
        ushort4 o0, o1;
        o0.x = f2bf(a.x); o0.y = f2bf(a.y); o0.z = f2bf(a.z); o0.w = f2bf(a.w);
        o1.x = f2bf(b.x); o1.y = f2bf(b.y); o1.z = f2bf(b.z); o1.w = f2bf(b.w);
        *(ushort4*)(dst + off)     = o0;
        *(ushort4*)(dst + off + 4) = o1;
    }
}

// ---------------- BMxBN bf16 GEMM, dbuf LDS + counted-vmcnt barriers ----------------
template <int BM, int BN, int EPI>
__global__ __launch_bounds__(BM == 256 ? 512 : 256)
void gemm2_kernel(const unsigned short* __restrict__ A,
                  const unsigned short* __restrict__ Bt,
                  const float* __restrict__ bias,
                  float* __restrict__ outF,
                  unsigned short* __restrict__ qb,
                  unsigned short* __restrict__ kb,
                  unsigned short* __restrict__ vt,
                  int N) {
    constexpr int K  = DM;
    constexpr int NW = (BM == 256) ? 8 : 4;      // waves per block
    constexpr int NWN = NW / 2;                  // wave-grid N count (2M x NWN)
    constexpr int WM = BM / 2;                   // wave M span
    constexpr int WN = BN / NWN;                 // wave N span
    constexpr int MR = WM / 16;                  // M frags per wave
    constexpr int FC = WN / 16;                  // N frags per wave
    constexpr int NT = K / 64;                   // 16 K-tiles
    constexpr int LPS = (BM + BN) / NW / 8;      // gload_lds per wave per STAGE
    __shared__ unsigned short Al[2][BM * 64];
    __shared__ unsigned short Bl[2][BN * 64];
    const int nbn = N / BN;
    const int cpx = gridDim.x >> 3;
    const int sid = (blockIdx.x & 7) * cpx + (blockIdx.x >> 3);
    const int bm = sid / nbn;
    const int bn = sid % nbn;
    const int tid = threadIdx.x;
    const int w = tid >> 6, lane = tid & 63;
    const int l15 = lane & 15, l4 = lane >> 4;
    const int wm = w / NWN, wn = w % NWN;
    const unsigned short* Ab = A  + (size_t)bm * BM * K;
    const unsigned short* Bb = Bt + (size_t)bn * BN * K;
    const int srow8  = lane >> 3;
    const int schunk = ((lane & 7) ^ (srow8 & 7)) * 8;
    const int swz    = l15 & 7;

    v4f acc[MR][FC] = {};

    auto STAGE = [&](int buf, int t) {
        const int k0 = t * 64;
        #pragma unroll
        for (int i = 0; i < BM / 8 / NW; ++i) {
            const int r0 = w * (BM / NW) + i * 8;
            gload_lds16(Ab + (size_t)(r0 + srow8) * K + k0 + schunk, &Al[buf][r0 * 64]);
        }
        #pragma unroll
        for (int i = 0; i < BN / 8 / NW; ++i) {
            const int r0 = w * (BN / NW) + i * 8;
            gload_lds16(Bb + (size_t)(r0 + srow8) * K + k0 + schunk, &Bl[buf][r0 * 64]);
        }
    };
    auto COMPUTE = [&](int buf) {
        #pragma unroll
        for (int ks = 0; ks < 2; ++ks) {
            v8s af[MR]; v8s bf[FC];
            #pragma unroll
            for (int m = 0; m < MR; ++m) {
                const int row = wm * WM + m * 16 + l15;
                af[m] = *(const v8s*)&Al[buf][row * 64 + ((ks * 4 + l4) ^ swz) * 8];
            }
            #pragma unroll
            for (int n = 0; n < FC; ++n) {
                const int row = wn * WN + n * 16 + l15;
                bf[n] = *(const v8s*)&Bl[buf][row * 64 + ((ks * 4 + l4) ^ swz) * 8];
            }
            #pragma unroll
            for (int m = 0; m < MR; ++m)
                #pragma unroll
                for (int n = 0; n < FC; ++n)
                    acc[m][n] = __builtin_amdgcn_mfma_f32_16x16x32_bf16(af[m], bf[n], acc[m][n], 0, 0, 0);
        }
    };

    STAGE(0, 0);
    int cur = 0;
    for (int t = 0; t < NT; ++t) {
        if (t + 1 < NT) {
            STAGE(cur ^ 1, t + 1);
            if constexpr (LPS == 7)      asm volatile("s_waitcnt vmcnt(7)" ::: "memory");
            else if constexpr (LPS == 6) asm volatile("s_waitcnt vmcnt(6)" ::: "memory");
            else if constexpr (LPS == 5) asm volatile("s_waitcnt vmcnt(5)" ::: "memory");
            else                         asm volatile("s_waitcnt vmcnt(0)" ::: "memory");
        } else {
            asm volatile("s_waitcnt vmcnt(0)" ::: "memory");
        }
        __builtin_amdgcn_s_barrier();
        __builtin_amdgcn_sched_barrier(0);
        COMPUTE(cur);
        __builtin_amdgcn_s_barrier();
        cur ^= 1;
    }

    #pragma unroll
    for (int m = 0; m < MR; ++m) {
        #pragma unroll
        for (int n = 0; n < FC; ++n) {
            #pragma unroll
            for (int r = 0; r < 4; ++r) {
                const int row = bm * BM + wm * WM + m * 16 + l4 * 4 + r;
                const int col = bn * BN + wn * WN + n * 16 + l15;
                const float val = acc[m][n][r] + bias[col];
                if (EPI == 0) {
                    outF[(size_t)row * N + col] = val;
                } else {
                    const int lq = row >> 1, b = row & 1;      // row = l*B + b
                    const int which = col >> 10, jr = col & 1023;
                    const int h = jr >> 6, d = jr & 63;
                    const int bh = b * NHD + h;
                    if (which == 0)      qb[((size_t)bh * LSEQ + lq) * HD + d] = f2bf(val * QSCALE);
                    else if (which == 1) kb[((size_t)bh * LSEQ + lq) * HD + d] = f2bf(val);
                    else                 vt[((size_t)bh * HD + d) * LSEQ + lq] = f2bf(val);
                }
            }
        }
    }
}

// ---------------- flash attention: swapped QK^T (32x32), in-register P ----------------
// Counted-vmcnt pipeline (r13 template): STAGE(t+1) -> vmcnt(4) [tile t's 4 loads done;
// t+1's stay in flight across both barriers] -> s_barrier -> compute -> s_barrier.
// Mask bias in MFMA C-init; permlane32_swap P-frags; setprio on MFMA clusters.
__global__ __launch_bounds__(256) void attn_kernel(const unsigned short* __restrict__ qbuf,
                                                   const unsigned short* __restrict__ kbuf,
                                                   const unsigned short* __restrict__ vtbuf,
                                                   const int* __restrict__ amask,
                                                   unsigned short* __restrict__ ctx) {
    __shared__ unsigned short Kl[2][64 * 64];
    __shared__ unsigned short Vl[2][64 * 64];
    __shared__ alignas(16) float mb_all[LSEQ];
    __shared__ alignas(16) float inv_l[4 * 32];
    const int id = blockIdx.x;
    const int inner = id >> 3;
    const int bh = (id & 7) * 4 + (inner & 3);
    const int qblk = inner >> 2;
    const int bat = bh >> 4, h = bh & 15;
    const int tid = threadIdx.x;
    const int w = tid >> 6, lane = tid & 63;
    const int l31 = lane & 31, hi = lane >> 5;
    const int q0 = qblk * 128 + w * 32;

    #pragma unroll
    for (int i = 0; i < LSEQ / 256; ++i)
        mb_all[i * 256 + tid] = amask[bat * LSEQ + i * 256 + tid] ? NEGM : -1e30f;

    const unsigned short* Qp = qbuf + ((size_t)bh * LSEQ + q0 + l31) * HD + hi * 8;
    v8s qfr[4];
    #pragma unroll
    for (int s = 0; s < 4; ++s) qfr[s] = *(const v8s*)(Qp + s * 16);

    const unsigned short* Kb = kbuf  + (size_t)bh * LSEQ * HD;
    const unsigned short* Vb = vtbuf + (size_t)bh * HD * LSEQ;

    v16f O0 = {}, O1 = {};
    float ls0 = 0.f, ls1 = 0.f, ls2 = 0.f, ls3 = 0.f;

    const int srow = lane >> 3;
    const int schunk = ((lane & 7) ^ srow) * 8;
    const int rsw = l31 & 7;

    auto STAGE = [&](int buf, int kv0) {
        const int r0 = w * 16;
        gload_lds16(Kb + (size_t)(kv0 + r0 + srow) * HD + schunk,       &Kl[buf][r0 * 64]);
        gload_lds16(Kb + (size_t)(kv0 + r0 + 8 + srow) * HD + schunk,   &Kl[buf][(r0 + 8) * 64]);
        gload_lds16(Vb + (size_t)(r0 + srow) * LSEQ + kv0 + schunk,     &Vl[buf][r0 * 64]);
        gload_lds16(Vb + (size_t)(r0 + 8 + srow) * LSEQ + kv0 + schunk, &Vl[buf][(r0 + 8) * 64]);
    };

    STAGE(0, 0);
    __syncthreads();                       // drains tile0 loads + mb_all writes (once)
    int cur = 0;
    for (int t = 0; t < LSEQ / 64; ++t) {
        if (t + 1 < LSEQ / 64) {
            STAGE(cur ^ 1, (t + 1) * 64);  // 4 loads issued; 8 outstanding
            asm volatile("s_waitcnt vmcnt(4)" ::: "memory");   // tile t's 4 landed
        } else {
            asm volatile("s_waitcnt vmcnt(0)" ::: "memory");
        }
        __builtin_amdgcn_s_barrier();      // publish tile t across waves
        __builtin_amdgcn_sched_barrier(0);
        const int kv0 = t * 64;

        #pragma unroll
        for (int kvh = 0; kvh < 2; ++kvh) {
            float4 mbv[4];
            #pragma unroll
            for (int g = 0; g < 4; ++g)
                mbv[g] = *(const float4*)&mb_all[kv0 + kvh * 32 + g * 8 + hi * 4];
            v16f sc;
            #pragma unroll
            for (int g = 0; g < 4; ++g) {
                sc[g * 4 + 0] = mbv[g].x;
                sc[g * 4 + 1] = mbv[g].y;
                sc[g * 4 + 2] = mbv[g].z;
                sc[g * 4 + 3] = mbv[g].w;
            }
            v8s kf[4];
            #pragma unroll
            for (int s = 0; s < 4; ++s)
                kf[s] = *(const v8s*)&Kl[cur][(kvh * 32 + l31) * 64 + ((2 * s + hi) ^ rsw) * 8];
            __builtin_amdgcn_s_setprio(1);
            #pragma unroll
            for (int s = 0; s < 4; ++s)
                sc = __builtin_amdgcn_mfma_f32_32x32x16_bf16(kf[s], qfr[s], sc, 0, 0, 0);
            __builtin_amdgcn_s_setprio(0);
            float pf[16];
            #pragma unroll
            for (int g = 0; g < 4; ++g) {
                const float p0 = EXP2F(sc[g * 4 + 0]);
                const float p1 = EXP2F(sc[g * 4 + 1]);
                const float p2 = EXP2F(sc[g * 4 + 2]);
                const float p3 = EXP2F(sc[g * 4 + 3]);
                pf[g * 4 + 0] = p0; pf[g * 4 + 1] = p1;
                pf[g * 4 + 2] = p2; pf[g * 4 + 3] = p3;
                ls0 += p0; ls1 += p1; ls2 += p2; ls3 += p3;
            }
            #pragma unroll
            for (int c = 0; c < 2; ++c) {
                unsigned int W[4];
                #pragma unroll
                for (int k = 0; k < 4; ++k)
                    asm("v_cvt_pk_bf16_f32 %0, %1, %2"
                        : "=v"(W[k]) : "v"(pf[8 * c + 2 * k]), "v"(pf[8 * c + 2 * k + 1]));
                v4u fw;
#if __has_builtin(__builtin_amdgcn_permlane32_swap)
                const v2u r02 = __builtin_amdgcn_permlane32_swap(W[0], W[2], false, false);
                const v2u r13 = __builtin_amdgcn_permlane32_swap(W[1], W[3], false, false);
                fw.x = r02.x; fw.y = r13.x; fw.z = r02.y; fw.w = r13.y;
#else
                const unsigned int sel0 = hi ? W[0] : W[2];
                const unsigned int sel1 = hi ? W[1] : W[3];
                const unsigned int S0 = (unsigned int)__shfl_xor((int)sel0, 32);
                const unsigned int S1 = (unsigned int)__shfl_xor((int)sel1, 32);
                fw.x = hi ? S0 : W[0];
                fw.y = hi ? S1 : W[1];
                fw.z = hi ? W[2] : S0;
                fw.w = hi ? W[3] : S1;
#endif
                const v8s pa = __builtin_bit_cast(v8s, fw);
                const int vch = (kvh * 4 + c * 2 + hi);
                const v8s vf0 = *(const v8s*)&Vl[cur][(l31) * 64      + (vch ^ rsw) * 8];
                const v8s vf1 = *(const v8s*)&Vl[cur][(32 + l31) * 64 + (vch ^ rsw) * 8];
                __builtin_amdgcn_s_setprio(1);
                O0 = __builtin_amdgcn_mfma_f32_32x32x16_bf16(pa, vf0, O0, 0, 0, 0);
                O1 = __builtin_amdgcn_mfma_f32_32x32x16_bf16(pa, vf1, O1, 0, 0, 0);
                __builtin_amdgcn_s_setprio(0);
            }
        }
        __builtin_amdgcn_s_barrier();      // reads of buf cur done before t+2 overwrites
        cur ^= 1;
    }

    float lsum = (ls0 + ls1) + (ls2 + ls3);
    lsum += __shfl_xor(lsum, 32);
    if (hi == 0) inv_l[w * 32 + l31] = 1.0f / lsum;
    asm volatile("s_waitcnt lgkmcnt(0)" ::: "memory");
    __builtin_amdgcn_sched_barrier(0);

    #pragma unroll
    for (int g = 0; g < 4; ++g) {
        const float4 iv = *(const float4*)&inv_l[w * 32 + g * 8 + hi * 4];
        #pragma unroll
        for (int bq = 0; bq < 4; ++bq) {
            const float ivx = (bq == 0) ? iv.x : (bq == 1) ? iv.y : (bq == 2) ? iv.z : iv.w;
            const int lq = q0 + g * 8 + hi * 4 + bq;
            unsigned short* crow = ctx + ((size_t)lq * BB + bat) * DM + h * HD;
            crow[l31]      = f2bf(O0[g * 4 + bq] * ivx);
            crow[32 + l31] = f2bf(O1[g * 4 + bq] * ivx);
        }
    }
}

extern "C" void kernel_launch(void* const* d_in, const int* in_sizes, int n_in,
                              void* d_out, int out_size, void* d_ws, size_t ws_size,
                              hipStream_t stream) {
    (void)in_sizes; (void)n_in; (void)out_size; (void)ws_size;
    const float* x     = (const float*)d_in[0];
    const int*   amask = (const int*)d_in[1];
    const float* ln_w  = (const float*)d_in[2];
    const float* ln_b  = (const float*)d_in[3];
    const float* qkv_w = (const float*)d_in[4];
    const float* qkv_b = (const float*)d_in[5];
    const float* out_w = (const float*)d_in[6];
    const float* out_b = (const float*)d_in[7];
    float* out = (float*)d_out;

    unsigned short* ws    = (unsigned short*)d_ws;
    unsigned short* xn    = ws;                                   // 4096*1024
    unsigned short* wq    = xn + (size_t)ROWS * DM;               // 3072*1024
    unsigned short* wo    = wq + (size_t)NQKV * DM;               // 1024*1024
    unsigned short* qbuf  = wo + (size_t)DM * DM;                 // 32*2048*64
    unsigned short* kbuf  = qbuf + (size_t)BB * NHD * LSEQ * HD;
    unsigned short* vtbuf = kbuf + (size_t)BB * NHD * LSEQ * HD;
    unsigned short* ctx   = vtbuf + (size_t)BB * NHD * LSEQ * HD; // 4096*1024

    prod_kernel<<<ROWS + 2048, 256, 0, stream>>>(x, ln_w, ln_b, qkv_w, out_w, xn, wq, wo);
    gemm2_kernel<256, 192, 1><<<(ROWS / 256) * (NQKV / 192), 512, 0, stream>>>(
        xn, wq, qkv_b, nullptr, qbuf, kbuf, vtbuf, NQKV);
    attn_kernel<<<512, 256, 0, stream>>>(qbuf, kbuf, vtbuf, amask, ctx);
    gemm2_kernel<128, 64, 0><<<(ROWS / 128) * (DM / 64), 256, 0, stream>>>(
        ctx, wo, out_b, out, nullptr, nullptr, nullptr, DM);
}